// Round 4
// baseline (75.968 us; speedup 1.0000x reference)
//
#include <hip/hip_runtime.h>
#include <hip/hip_bf16.h>
#include <math.h>

#define B_ 16
#define T_ 32
#define L_ 128
#define D_ 768
#define NH_ 12
#define HD_ 64
#define M_ (B_*T_)   // 512

typedef __attribute__((ext_vector_type(8))) short s16x8;
typedef __attribute__((ext_vector_type(4))) float f32x4;
typedef __attribute__((ext_vector_type(8))) unsigned short u16x8;

__device__ __forceinline__ unsigned short f2bf(float x) {
    unsigned int b = __float_as_uint(x);
    b += 0x7FFFu + ((b >> 16) & 1u);   // RNE (finite inputs)
    return (unsigned short)(b >> 16);
}

#define MFMA16(a, b, c) __builtin_amdgcn_mfma_f32_16x16x32_bf16(a, b, c, 0, 0, 0)

// ---- fused: pool partials (blocks 0..2047) + weight prep (blocks 2048..3583) ----
// Pool part: block bx<2048 handles (bt = bx>>2) rows [32*(bx&3), +32): partial sums.
// Prep: transpose+convert W{q,k,v,o} to n-major bf16, 48x32 tiles, 384 threads.
__global__ __launch_bounds__(384) void pool_prep_kernel(
    const int* __restrict__ ids, const float* __restrict__ amask,
    const float* __restrict__ embed,
    const float* __restrict__ Wq, const float* __restrict__ Wk,
    const float* __restrict__ Wv, const float* __restrict__ Wo,
    unsigned short* __restrict__ Wt, unsigned short* __restrict__ Wot,
    float* __restrict__ Ppart, float* __restrict__ PartM,
    int* __restrict__ cnt)
{
    const int bx  = blockIdx.x;
    const int tid = threadIdx.x;
    if (bx < M_*4) {
        const int bt = bx >> 2, l0 = (bx & 3) * 32;
        const int tx = tid % 96, ph = tid / 96;
        __shared__ int   sid[32];
        __shared__ float smk[32];
        __shared__ float red[4][96][9];
        if (tid < 32) {
            sid[tid] = ids[bt*L_ + l0 + tid];
            smk[tid] = amask[bt*L_ + l0 + tid];
        } else if (bx == 0 && tid >= 64 && tid < 72) {
            cnt[tid - 64] = 0;          // zero K4's per-m-group counters (stream-ordered)
        }
        __syncthreads();
        float a0=0,a1=0,a2=0,a3=0,a4=0,a5=0,a6=0,a7=0, msump=0.f;
        #pragma unroll 8
        for (int l = ph; l < 32; l += 4) {
            float m = smk[l];
            msump += m;
            const float4* p = (const float4*)(embed + (size_t)sid[l]*D_) + (tx << 1);
            float4 v0 = p[0], v1 = p[1];
            a0 = fmaf(v0.x, m, a0); a1 = fmaf(v0.y, m, a1);
            a2 = fmaf(v0.z, m, a2); a3 = fmaf(v0.w, m, a3);
            a4 = fmaf(v1.x, m, a4); a5 = fmaf(v1.y, m, a5);
            a6 = fmaf(v1.z, m, a6); a7 = fmaf(v1.w, m, a7);
        }
        float* rr = red[ph][tx];
        rr[0]=a0; rr[1]=a1; rr[2]=a2; rr[3]=a3; rr[4]=a4; rr[5]=a5; rr[6]=a6; rr[7]=a7;
        if (tx == 0) rr[8] = msump;      // stash partial msum in pad slot
        __syncthreads();
        if (ph == 0) {
            float4 o0, o1;
            o0.x = red[0][tx][0]+red[1][tx][0]+red[2][tx][0]+red[3][tx][0];
            o0.y = red[0][tx][1]+red[1][tx][1]+red[2][tx][1]+red[3][tx][1];
            o0.z = red[0][tx][2]+red[1][tx][2]+red[2][tx][2]+red[3][tx][2];
            o0.w = red[0][tx][3]+red[1][tx][3]+red[2][tx][3]+red[3][tx][3];
            o1.x = red[0][tx][4]+red[1][tx][4]+red[2][tx][4]+red[3][tx][4];
            o1.y = red[0][tx][5]+red[1][tx][5]+red[2][tx][5]+red[3][tx][5];
            o1.z = red[0][tx][6]+red[1][tx][6]+red[2][tx][6]+red[3][tx][6];
            o1.w = red[0][tx][7]+red[1][tx][7]+red[2][tx][7]+red[3][tx][7];
            float* dst = Ppart + (size_t)bx*D_ + tx*8;
            *(float4*)dst = o0;
            *(float4*)(dst + 4) = o1;
            if (tx == 0)
                PartM[bx] = red[0][0][8]+red[1][0][8]+red[2][0][8]+red[3][0][8];
        }
    } else {
        const int idx = bx - M_*4;         // 0..1535
        const int z   = idx / 384;         // 0..3 (Wq,Wk,Wv,Wo)
        const int rem = idx % 384;         // 16 n-tiles x 24 k-tiles
        const int n0  = (rem % 16) * 48;
        const int k0  = (rem / 16) * 32;
        const float* __restrict__ W = (z==0)?Wq:(z==1)?Wk:(z==2)?Wv:Wo;
        unsigned short* __restrict__ outp = (z<3) ? (Wt + (size_t)z*D_*D_) : Wot;
        __shared__ float tile[32][49];
        {
            const int tx2 = tid % 48, ty2 = tid / 48;   // (48, 8)
            #pragma unroll
            for (int r = 0; r < 4; ++r)
                tile[ty2 + r*8][tx2] = W[(size_t)(k0 + ty2 + r*8)*D_ + n0 + tx2];
        }
        __syncthreads();
        {
            const int tk = tid % 32, tn = tid / 32;     // (32, 12)
            #pragma unroll
            for (int r = 0; r < 4; ++r)
                outp[(size_t)(n0 + tn + r*12)*D_ + k0 + tk] = f2bf(tile[tk][tn + r*12]);
        }
    }
}

// ---- combine partials -> Hbf (bf16) + s1 = H·Wh[0:768] ----
__global__ __launch_bounds__(96) void combine_kernel(
    const float* __restrict__ Ppart, const float* __restrict__ PartM,
    const float* __restrict__ Wh,
    unsigned short* __restrict__ Hbf, float* __restrict__ s1)
{
    const int bt = blockIdx.x, tx = threadIdx.x;   // 96 threads
    __shared__ float dp[96];
    float msum = PartM[bt*4] + PartM[bt*4+1] + PartM[bt*4+2] + PartM[bt*4+3];
    float inv = 1.f / fmaxf(msum, 1.f);
    const float* p0 = Ppart + (size_t)(bt*4)*D_ + tx*8;
    float s[8];
    #pragma unroll
    for (int k = 0; k < 8; ++k)
        s[k] = (p0[k] + p0[D_ + k] + p0[2*D_ + k] + p0[3*D_ + k]) * inv;
    u16x8 hb;
    #pragma unroll
    for (int k = 0; k < 8; ++k) hb[k] = f2bf(s[k]);
    *(u16x8*)(Hbf + (size_t)bt*D_ + tx*8) = hb;
    float d = 0.f;
    #pragma unroll
    for (int k = 0; k < 8; ++k) d = fmaf(s[k], Wh[tx*8 + k], d);
    dp[tx] = d;
    __syncthreads();
    if (tx < 32) {
        float dd = dp[tx] + dp[tx+32] + dp[tx+64];
        #pragma unroll
        for (int off = 16; off > 0; off >>= 1) dd += __shfl_xor(dd, off, 32);
        if (tx == 0) s1[bt] = dd;
    }
}

// -------- fused QKV projection + causal attention: one block per (b,h) ----------
__global__ __launch_bounds__(256) void qkv_attn_kernel(
    const unsigned short* __restrict__ Hbf,   // [512][768] bf16
    const unsigned short* __restrict__ Wt,    // [2304][768] bf16 n-major
    const float* __restrict__ bq, const float* __restrict__ bk, const float* __restrict__ bv,
    const float* __restrict__ tmask,
    unsigned short* __restrict__ ctx)         // [512][768] bf16
{
    const int b = blockIdx.x / NH_;
    const int h = blockIdx.x % NH_;
    const int tid  = threadIdx.x;
    const int lane = tid & 63;
    const int w    = tid >> 6;      // wave 0..3
    const int r16  = lane & 15;
    const int kgrp = lane >> 4;     // 0..3

    __shared__ unsigned short Hs[32][776];
    __shared__ unsigned short Qs[32][72];
    __shared__ unsigned short Ks[32][72];
    __shared__ unsigned short Vt[64][40];
    __shared__ unsigned short Ps[32][40];

    const unsigned short* hsrc = Hbf + (size_t)b*T_*D_;
    #pragma unroll
    for (int it = 0; it < 12; ++it) {
        int e = it*256 + tid;
        int row = e / 96, cg = e % 96;
        *(s16x8*)&Hs[row][cg*8] = *(const s16x8*)(hsrc + row*D_ + cg*8);
    }
    __syncthreads();

    const int nc = h*HD_ + w*16 + r16;
    const unsigned short* wq = Wt + (size_t)nc*D_;
    const unsigned short* wk = wq + (size_t)D_*D_;
    const unsigned short* wv = wk + (size_t)D_*D_;
    f32x4 aQ0={0,0,0,0},aQ1={0,0,0,0},aK0={0,0,0,0},aK1={0,0,0,0},aV0={0,0,0,0},aV1={0,0,0,0};
    s16x8 pq = *(const s16x8*)(wq + kgrp*8);
    s16x8 pk = *(const s16x8*)(wk + kgrp*8);
    s16x8 pv = *(const s16x8*)(wv + kgrp*8);
    for (int k0 = 0; k0 < D_; k0 += 32) {
        s16x8 cq = pq, ck = pk, cv = pv;
        int kn = k0 + 32;
        if (kn < D_) {
            pq = *(const s16x8*)(wq + kn + kgrp*8);
            pk = *(const s16x8*)(wk + kn + kgrp*8);
            pv = *(const s16x8*)(wv + kn + kgrp*8);
        }
        s16x8 a0 = *(const s16x8*)&Hs[r16][k0 + kgrp*8];
        s16x8 a1 = *(const s16x8*)&Hs[16 + r16][k0 + kgrp*8];
        aQ0 = MFMA16(a0, cq, aQ0); aQ1 = MFMA16(a1, cq, aQ1);
        aK0 = MFMA16(a0, ck, aK0); aK1 = MFMA16(a1, ck, aK1);
        aV0 = MFMA16(a0, cv, aV0); aV1 = MFMA16(a1, cv, aV1);
    }
    {
        const int c = w*16 + r16;
        const float bQ = bq[h*HD_ + c], bK = bk[h*HD_ + c], bV = bv[h*HD_ + c];
        #pragma unroll
        for (int mi = 0; mi < 2; ++mi) {
            f32x4 q_ = mi ? aQ1 : aQ0;
            f32x4 k_ = mi ? aK1 : aK0;
            f32x4 v_ = mi ? aV1 : aV0;
            #pragma unroll
            for (int r = 0; r < 4; ++r) {
                int i = mi*16 + kgrp*4 + r;
                Qs[i][c] = f2bf(q_[r] + bQ);
                Ks[i][c] = f2bf(k_[r] + bK);
                Vt[c][i] = f2bf(v_[r] + bV);
            }
        }
    }
    __syncthreads();

    f32x4 s00={0,0,0,0}, s01={0,0,0,0}, s10={0,0,0,0}, s11={0,0,0,0};
    #pragma unroll
    for (int ks = 0; ks < 2; ++ks) {
        s16x8 q0 = *(const s16x8*)&Qs[r16][ks*32 + kgrp*8];
        s16x8 q1 = *(const s16x8*)&Qs[16 + r16][ks*32 + kgrp*8];
        s16x8 k0v = *(const s16x8*)&Ks[r16][ks*32 + kgrp*8];
        s16x8 k1v = *(const s16x8*)&Ks[16 + r16][ks*32 + kgrp*8];
        s00 = MFMA16(q0, k0v, s00); s01 = MFMA16(q0, k1v, s01);
        s10 = MFMA16(q1, k0v, s10); s11 = MFMA16(q1, k1v, s11);
    }

    const float tmj0 = tmask[b*T_ + r16];
    const float tmj1 = tmask[b*T_ + 16 + r16];
    const int miW = w >> 1, niW = w & 1;
    #pragma unroll
    for (int mi = 0; mi < 2; ++mi) {
        f32x4 sv0 = mi ? s10 : s00;
        f32x4 sv1 = mi ? s11 : s01;
        #pragma unroll
        for (int r = 0; r < 4; ++r) {
            int i = mi*16 + kgrp*4 + r;
            float v0 = (r16 < i      && tmj0 > 0.f) ? sv0[r]*0.125f : -1e9f;
            float v1 = (16 + r16 < i && tmj1 > 0.f) ? sv1[r]*0.125f : -1e9f;
            float mx = fmaxf(v0, v1);
            #pragma unroll
            for (int off = 1; off < 16; off <<= 1) mx = fmaxf(mx, __shfl_xor(mx, off));
            float e0 = __expf(v0 - mx), e1 = __expf(v1 - mx);
            float sm = e0 + e1;
            #pragma unroll
            for (int off = 1; off < 16; off <<= 1) sm += __shfl_xor(sm, off);
            float inv = 1.f / sm;
            if (mi == miW) {
                float p = (niW ? e1 : e0) * inv;
                Ps[i][niW*16 + r16] = f2bf(p);
            }
        }
    }
    __syncthreads();

    {
        s16x8 ap0 = *(const s16x8*)&Ps[r16][kgrp*8];
        s16x8 ap1 = *(const s16x8*)&Ps[16 + r16][kgrp*8];
        s16x8 bvv = *(const s16x8*)&Vt[w*16 + r16][kgrp*8];
        f32x4 o0 = {0,0,0,0}, o1 = {0,0,0,0};
        o0 = MFMA16(ap0, bvv, o0);
        o1 = MFMA16(ap1, bvv, o1);
        #pragma unroll
        for (int mi = 0; mi < 2; ++mi) {
            f32x4 o_ = mi ? o1 : o0;
            #pragma unroll
            for (int r = 0; r < 4; ++r) {
                int i = mi*16 + kgrp*4 + r;
                ctx[(size_t)(b*T_ + i)*D_ + h*HD_ + w*16 + r16] = f2bf(o_[r]);
            }
        }
    }
}

// ---- Wo GEMM + head-part-2 (R0 internals, LDS-staged) + fused final scan:
//      the 12th bn-block of each m-group runs sigmoid/noisy-or for its 64 rows ----
__global__ __launch_bounds__(256) void gemm_head_scan_kernel(
    const unsigned short* __restrict__ Abf,   // CTXbf [512][768]
    const unsigned short* __restrict__ Wtn,   // Wot [768][768] n-major
    const float* __restrict__ bias,           // bo
    const float* __restrict__ Wh,             // [1536]
    const float* __restrict__ s1,
    const float* __restrict__ bh,
    const float* __restrict__ tmask,
    int* __restrict__ cnt,                    // [8], zeroed by K1
    float* __restrict__ s2p,                  // [512][12]
    float* __restrict__ qprob, float* __restrict__ p_agg, float* __restrict__ p_dlg)
{
    const int bn = blockIdx.x;          // 0..11
    const int n0 = bn * 64;
    const int m0 = blockIdx.y * 64;

    __shared__ unsigned short As[64][40];
    __shared__ unsigned short Bs[64][40];
    __shared__ float s2l[64][2];
    __shared__ int sdone;

    const int tid  = threadIdx.x;
    const int lane = tid & 63;
    const int wave = tid >> 6;
    const int wm   = wave >> 1;
    const int wn   = wave & 1;
    const int kgrp = lane >> 4;
    const int r16  = lane & 15;

    const int srow = tid >> 2;
    const int scol = (tid & 3) * 8;

    f32x4 acc00 = {0,0,0,0}, acc01 = {0,0,0,0}, acc10 = {0,0,0,0}, acc11 = {0,0,0,0};

    for (int k0 = 0; k0 < D_; k0 += 32) {
        s16x8 av = *(const s16x8*)(Abf + (size_t)(m0 + srow)*D_ + k0 + scol);
        s16x8 bv = *(const s16x8*)(Wtn + (size_t)(n0 + srow)*D_ + k0 + scol);
        *(s16x8*)&As[srow][scol] = av;
        *(s16x8*)&Bs[srow][scol] = bv;
        __syncthreads();
        s16x8 a0 = *(const s16x8*)&As[wm*32 +      r16][kgrp*8];
        s16x8 a1 = *(const s16x8*)&As[wm*32 + 16 + r16][kgrp*8];
        s16x8 bb0 = *(const s16x8*)&Bs[wn*32 +      r16][kgrp*8];
        s16x8 bb1 = *(const s16x8*)&Bs[wn*32 + 16 + r16][kgrp*8];
        acc00 = MFMA16(a0, bb0, acc00);
        acc01 = MFMA16(a0, bb1, acc01);
        acc10 = MFMA16(a1, bb0, acc10);
        acc11 = MFMA16(a1, bb1, acc11);
        __syncthreads();
    }

    float rp[2][4] = {};
    #pragma unroll
    for (int ni = 0; ni < 2; ++ni) {
        int col = n0 + wn*32 + ni*16 + r16;
        float w2 = Wh[D_ + col];
        float bv_ = bias[col];
        #pragma unroll
        for (int mi = 0; mi < 2; ++mi) {
            f32x4 c = (mi == 0) ? (ni == 0 ? acc00 : acc01) : (ni == 0 ? acc10 : acc11);
            #pragma unroll
            for (int r = 0; r < 4; ++r) {
                int m = m0 + wm*32 + mi*16 + kgrp*4 + r;
                float v = c[r] + bv_;
                if ((m & (T_ - 1)) == 0) v = 0.f;   // t == 0
                rp[mi][r] = fmaf(v, w2, rp[mi][r]);
            }
        }
    }
    #pragma unroll
    for (int mi = 0; mi < 2; ++mi)
        #pragma unroll
        for (int r = 0; r < 4; ++r) {
            float v = rp[mi][r];
            v += __shfl_xor(v, 1); v += __shfl_xor(v, 2);
            v += __shfl_xor(v, 4); v += __shfl_xor(v, 8);
            rp[mi][r] = v;
        }
    if (r16 == 0) {
        #pragma unroll
        for (int mi = 0; mi < 2; ++mi)
            #pragma unroll
            for (int r = 0; r < 4; ++r)
                s2l[wm*32 + mi*16 + kgrp*4 + r][wn] = rp[mi][r];
    }
    __syncthreads();
    if (tid < 64)
        s2p[(size_t)(m0 + tid)*12 + bn] = s2l[tid][0] + s2l[tid][1];

    // ---- last-block-done: the 12th bn block of this m-group runs the scan ----
    __threadfence();                         // release: push s2p writes device-wide
    __syncthreads();                         // all writers' fences complete
    if (tid == 0)
        sdone = (atomicAdd(cnt + blockIdx.y, 1) == 11) ? 1 : 0;
    __syncthreads();
    if (sdone) {
        __threadfence();                     // acquire: invalidate stale cache lines
        if (tid < 64) {
            const int m = m0 + tid;
            float s = s1[m] + bh[0];
            #pragma unroll
            for (int c = 0; c < 12; ++c) s += s2p[(size_t)m*12 + c];
            float q = (1.f / (1.f + __expf(-s))) * tmask[m];
            qprob[m] = q;
            float x = 1.f - q;
            const int t = tid & 31;
            #pragma unroll
            for (int off = 1; off < 32; off <<= 1) {
                float y = __shfl_up(x, off, 32);
                if (t >= off) x *= y;
            }
            p_agg[m] = 1.f - x;
            if (t == 31) p_dlg[m >> 5] = 1.f - x;
        }
    }
}

extern "C" void kernel_launch(void* const* d_in, const int* in_sizes, int n_in,
                              void* d_out, int out_size, void* d_ws, size_t ws_size,
                              hipStream_t stream) {
    const int*   ids   = (const int*)  d_in[0];
    const float* amask = (const float*)d_in[1];
    const float* tmask = (const float*)d_in[2];
    const float* embed = (const float*)d_in[3];
    const float* Wq    = (const float*)d_in[4];
    const float* bq    = (const float*)d_in[5];
    const float* Wk    = (const float*)d_in[6];
    const float* bk    = (const float*)d_in[7];
    const float* Wv    = (const float*)d_in[8];
    const float* bv    = (const float*)d_in[9];
    const float* Wo    = (const float*)d_in[10];
    const float* bo    = (const float*)d_in[11];
    const float* Wh    = (const float*)d_in[12];
    const float* bh    = (const float*)d_in[13];
    float* out = (float*)d_out;

    unsigned short* Hbf   = (unsigned short*)d_ws;          // [512][768]
    unsigned short* CTXbf = Hbf + (size_t)M_*D_;            // [512][768]
    unsigned short* Wt    = CTXbf + (size_t)M_*D_;          // [2304][768]
    unsigned short* Wot   = Wt + (size_t)3*D_*D_;           // [768][768]
    float* s1    = (float*)(Wot + (size_t)D_*D_);           // [512]
    float* s2p   = s1 + M_;                                 // [512][12]
    int*   cnt   = (int*)(s2p + M_*12);                     // [8]
    float* PartM = (float*)(cnt + 8);                       // [2048]
    float* Ppart = PartM + M_*4;                            // [2048][768]

    pool_prep_kernel<<<M_*4 + 1536, 384, 0, stream>>>(
        ids, amask, embed, Wq, Wk, Wv, Wo, Wt, Wot, Ppart, PartM, cnt);
    combine_kernel<<<M_, 96, 0, stream>>>(Ppart, PartM, Wh, Hbf, s1);
    qkv_attn_kernel<<<B_*NH_, 256, 0, stream>>>(Hbf, Wt, bq, bk, bv, tmask, CTXbf);
    gemm_head_scan_kernel<<<dim3(12, 8), 256, 0, stream>>>(
        CTXbf, Wot, bo, Wh, s1, bh, tmask, cnt, s2p, out, out + M_, out + 2*M_);
}

// Round 5
// 66.449 us; speedup vs baseline: 1.1433x; 1.1433x over previous
//
#include <hip/hip_runtime.h>
#include <hip/hip_bf16.h>
#include <math.h>

#define B_ 16
#define T_ 32
#define L_ 128
#define D_ 768
#define NH_ 12
#define HD_ 64
#define M_ (B_*T_)   // 512

typedef __attribute__((ext_vector_type(8))) short s16x8;
typedef __attribute__((ext_vector_type(4))) float f32x4;
typedef __attribute__((ext_vector_type(8))) unsigned short u16x8;

__device__ __forceinline__ unsigned short f2bf(float x) {
    unsigned int b = __float_as_uint(x);
    b += 0x7FFFu + ((b >> 16) & 1u);   // RNE (finite inputs)
    return (unsigned short)(b >> 16);
}

#define MFMA16(a, b, c) __builtin_amdgcn_mfma_f32_16x16x32_bf16(a, b, c, 0, 0, 0)

// ---- fused: pool partials (blocks 0..2047) + weight prep (blocks 2048..3583) ----
// Pool part: block bx<2048 handles (bt = bx>>2) rows [32*(bx&3), +32): partial sums.
// Prep: transpose+convert W{q,k,v,o} to n-major bf16, 48x32 tiles, 384 threads.
__global__ __launch_bounds__(384) void pool_prep_kernel(
    const int* __restrict__ ids, const float* __restrict__ amask,
    const float* __restrict__ embed,
    const float* __restrict__ Wq, const float* __restrict__ Wk,
    const float* __restrict__ Wv, const float* __restrict__ Wo,
    unsigned short* __restrict__ Wt, unsigned short* __restrict__ Wot,
    float* __restrict__ Ppart, float* __restrict__ PartM)
{
    const int bx  = blockIdx.x;
    const int tid = threadIdx.x;
    if (bx < M_*4) {
        const int bt = bx >> 2, l0 = (bx & 3) * 32;
        const int tx = tid % 96, ph = tid / 96;
        __shared__ int   sid[32];
        __shared__ float smk[32];
        __shared__ float red[4][96][9];
        if (tid < 32) {
            sid[tid] = ids[bt*L_ + l0 + tid];
            smk[tid] = amask[bt*L_ + l0 + tid];
        }
        __syncthreads();
        float a0=0,a1=0,a2=0,a3=0,a4=0,a5=0,a6=0,a7=0, msump=0.f;
        #pragma unroll 8
        for (int l = ph; l < 32; l += 4) {
            float m = smk[l];
            msump += m;
            const float4* p = (const float4*)(embed + (size_t)sid[l]*D_) + (tx << 1);
            float4 v0 = p[0], v1 = p[1];
            a0 = fmaf(v0.x, m, a0); a1 = fmaf(v0.y, m, a1);
            a2 = fmaf(v0.z, m, a2); a3 = fmaf(v0.w, m, a3);
            a4 = fmaf(v1.x, m, a4); a5 = fmaf(v1.y, m, a5);
            a6 = fmaf(v1.z, m, a6); a7 = fmaf(v1.w, m, a7);
        }
        float* rr = red[ph][tx];
        rr[0]=a0; rr[1]=a1; rr[2]=a2; rr[3]=a3; rr[4]=a4; rr[5]=a5; rr[6]=a6; rr[7]=a7;
        if (tx == 0) rr[8] = msump;      // stash partial msum in pad slot
        __syncthreads();
        if (ph == 0) {
            float4 o0, o1;
            o0.x = red[0][tx][0]+red[1][tx][0]+red[2][tx][0]+red[3][tx][0];
            o0.y = red[0][tx][1]+red[1][tx][1]+red[2][tx][1]+red[3][tx][1];
            o0.z = red[0][tx][2]+red[1][tx][2]+red[2][tx][2]+red[3][tx][2];
            o0.w = red[0][tx][3]+red[1][tx][3]+red[2][tx][3]+red[3][tx][3];
            o1.x = red[0][tx][4]+red[1][tx][4]+red[2][tx][4]+red[3][tx][4];
            o1.y = red[0][tx][5]+red[1][tx][5]+red[2][tx][5]+red[3][tx][5];
            o1.z = red[0][tx][6]+red[1][tx][6]+red[2][tx][6]+red[3][tx][6];
            o1.w = red[0][tx][7]+red[1][tx][7]+red[2][tx][7]+red[3][tx][7];
            float* dst = Ppart + (size_t)bx*D_ + tx*8;
            *(float4*)dst = o0;
            *(float4*)(dst + 4) = o1;
            if (tx == 0)
                PartM[bx] = red[0][0][8]+red[1][0][8]+red[2][0][8]+red[3][0][8];
        }
    } else {
        const int idx = bx - M_*4;         // 0..1535
        const int z   = idx / 384;         // 0..3 (Wq,Wk,Wv,Wo)
        const int rem = idx % 384;         // 16 n-tiles x 24 k-tiles
        const int n0  = (rem % 16) * 48;
        const int k0  = (rem / 16) * 32;
        const float* __restrict__ W = (z==0)?Wq:(z==1)?Wk:(z==2)?Wv:Wo;
        unsigned short* __restrict__ outp = (z<3) ? (Wt + (size_t)z*D_*D_) : Wot;
        __shared__ float tile[32][49];
        {
            const int tx2 = tid % 48, ty2 = tid / 48;   // (48, 8)
            #pragma unroll
            for (int r = 0; r < 4; ++r)
                tile[ty2 + r*8][tx2] = W[(size_t)(k0 + ty2 + r*8)*D_ + n0 + tx2];
        }
        __syncthreads();
        {
            const int tk = tid % 32, tn = tid / 32;     // (32, 12)
            #pragma unroll
            for (int r = 0; r < 4; ++r)
                outp[(size_t)(n0 + tn + r*12)*D_ + k0 + tk] = f2bf(tile[tk][tn + r*12]);
        }
    }
}

// ---- combine partials -> Hbf (bf16) + s1 = H·Wh[0:768] ----
__global__ __launch_bounds__(96) void combine_kernel(
    const float* __restrict__ Ppart, const float* __restrict__ PartM,
    const float* __restrict__ Wh,
    unsigned short* __restrict__ Hbf, float* __restrict__ s1)
{
    const int bt = blockIdx.x, tx = threadIdx.x;   // 96 threads
    __shared__ float dp[96];
    float msum = PartM[bt*4] + PartM[bt*4+1] + PartM[bt*4+2] + PartM[bt*4+3];
    float inv = 1.f / fmaxf(msum, 1.f);
    const float* p0 = Ppart + (size_t)(bt*4)*D_ + tx*8;
    float s[8];
    #pragma unroll
    for (int k = 0; k < 8; ++k)
        s[k] = (p0[k] + p0[D_ + k] + p0[2*D_ + k] + p0[3*D_ + k]) * inv;
    u16x8 hb;
    #pragma unroll
    for (int k = 0; k < 8; ++k) hb[k] = f2bf(s[k]);
    *(u16x8*)(Hbf + (size_t)bt*D_ + tx*8) = hb;
    float d = 0.f;
    #pragma unroll
    for (int k = 0; k < 8; ++k) d = fmaf(s[k], Wh[tx*8 + k], d);
    dp[tx] = d;
    __syncthreads();
    if (tx < 32) {
        float dd = dp[tx] + dp[tx+32] + dp[tx+64];
        #pragma unroll
        for (int off = 16; off > 0; off >>= 1) dd += __shfl_xor(dd, off, 32);
        if (tx == 0) s1[bt] = dd;
    }
}

// -------- fused QKV projection + causal attention: one block per (b,h) ----------
__global__ __launch_bounds__(256) void qkv_attn_kernel(
    const unsigned short* __restrict__ Hbf,   // [512][768] bf16
    const unsigned short* __restrict__ Wt,    // [2304][768] bf16 n-major
    const float* __restrict__ bq, const float* __restrict__ bk, const float* __restrict__ bv,
    const float* __restrict__ tmask,
    unsigned short* __restrict__ ctx)         // [512][768] bf16
{
    const int b = blockIdx.x / NH_;
    const int h = blockIdx.x % NH_;
    const int tid  = threadIdx.x;
    const int lane = tid & 63;
    const int w    = tid >> 6;      // wave 0..3
    const int r16  = lane & 15;
    const int kgrp = lane >> 4;     // 0..3

    __shared__ unsigned short Hs[32][776];
    __shared__ unsigned short Qs[32][72];
    __shared__ unsigned short Ks[32][72];
    __shared__ unsigned short Vt[64][40];
    __shared__ unsigned short Ps[32][40];

    const unsigned short* hsrc = Hbf + (size_t)b*T_*D_;
    #pragma unroll
    for (int it = 0; it < 12; ++it) {
        int e = it*256 + tid;
        int row = e / 96, cg = e % 96;
        *(s16x8*)&Hs[row][cg*8] = *(const s16x8*)(hsrc + row*D_ + cg*8);
    }
    __syncthreads();

    const int nc = h*HD_ + w*16 + r16;
    const unsigned short* wq = Wt + (size_t)nc*D_;
    const unsigned short* wk = wq + (size_t)D_*D_;
    const unsigned short* wv = wk + (size_t)D_*D_;
    f32x4 aQ0={0,0,0,0},aQ1={0,0,0,0},aK0={0,0,0,0},aK1={0,0,0,0},aV0={0,0,0,0},aV1={0,0,0,0};
    s16x8 pq = *(const s16x8*)(wq + kgrp*8);
    s16x8 pk = *(const s16x8*)(wk + kgrp*8);
    s16x8 pv = *(const s16x8*)(wv + kgrp*8);
    for (int k0 = 0; k0 < D_; k0 += 32) {
        s16x8 cq = pq, ck = pk, cv = pv;
        int kn = k0 + 32;
        if (kn < D_) {
            pq = *(const s16x8*)(wq + kn + kgrp*8);
            pk = *(const s16x8*)(wk + kn + kgrp*8);
            pv = *(const s16x8*)(wv + kn + kgrp*8);
        }
        s16x8 a0 = *(const s16x8*)&Hs[r16][k0 + kgrp*8];
        s16x8 a1 = *(const s16x8*)&Hs[16 + r16][k0 + kgrp*8];
        aQ0 = MFMA16(a0, cq, aQ0); aQ1 = MFMA16(a1, cq, aQ1);
        aK0 = MFMA16(a0, ck, aK0); aK1 = MFMA16(a1, ck, aK1);
        aV0 = MFMA16(a0, cv, aV0); aV1 = MFMA16(a1, cv, aV1);
    }
    {
        const int c = w*16 + r16;
        const float bQ = bq[h*HD_ + c], bK = bk[h*HD_ + c], bV = bv[h*HD_ + c];
        #pragma unroll
        for (int mi = 0; mi < 2; ++mi) {
            f32x4 q_ = mi ? aQ1 : aQ0;
            f32x4 k_ = mi ? aK1 : aK0;
            f32x4 v_ = mi ? aV1 : aV0;
            #pragma unroll
            for (int r = 0; r < 4; ++r) {
                int i = mi*16 + kgrp*4 + r;
                Qs[i][c] = f2bf(q_[r] + bQ);
                Ks[i][c] = f2bf(k_[r] + bK);
                Vt[c][i] = f2bf(v_[r] + bV);
            }
        }
    }
    __syncthreads();

    f32x4 s00={0,0,0,0}, s01={0,0,0,0}, s10={0,0,0,0}, s11={0,0,0,0};
    #pragma unroll
    for (int ks = 0; ks < 2; ++ks) {
        s16x8 q0 = *(const s16x8*)&Qs[r16][ks*32 + kgrp*8];
        s16x8 q1 = *(const s16x8*)&Qs[16 + r16][ks*32 + kgrp*8];
        s16x8 k0v = *(const s16x8*)&Ks[r16][ks*32 + kgrp*8];
        s16x8 k1v = *(const s16x8*)&Ks[16 + r16][ks*32 + kgrp*8];
        s00 = MFMA16(q0, k0v, s00); s01 = MFMA16(q0, k1v, s01);
        s10 = MFMA16(q1, k0v, s10); s11 = MFMA16(q1, k1v, s11);
    }

    const float tmj0 = tmask[b*T_ + r16];
    const float tmj1 = tmask[b*T_ + 16 + r16];
    const int miW = w >> 1, niW = w & 1;
    #pragma unroll
    for (int mi = 0; mi < 2; ++mi) {
        f32x4 sv0 = mi ? s10 : s00;
        f32x4 sv1 = mi ? s11 : s01;
        #pragma unroll
        for (int r = 0; r < 4; ++r) {
            int i = mi*16 + kgrp*4 + r;
            float v0 = (r16 < i      && tmj0 > 0.f) ? sv0[r]*0.125f : -1e9f;
            float v1 = (16 + r16 < i && tmj1 > 0.f) ? sv1[r]*0.125f : -1e9f;
            float mx = fmaxf(v0, v1);
            #pragma unroll
            for (int off = 1; off < 16; off <<= 1) mx = fmaxf(mx, __shfl_xor(mx, off));
            float e0 = __expf(v0 - mx), e1 = __expf(v1 - mx);
            float sm = e0 + e1;
            #pragma unroll
            for (int off = 1; off < 16; off <<= 1) sm += __shfl_xor(sm, off);
            float inv = 1.f / sm;
            if (mi == miW) {
                float p = (niW ? e1 : e0) * inv;
                Ps[i][niW*16 + r16] = f2bf(p);
            }
        }
    }
    __syncthreads();

    {
        s16x8 ap0 = *(const s16x8*)&Ps[r16][kgrp*8];
        s16x8 ap1 = *(const s16x8*)&Ps[16 + r16][kgrp*8];
        s16x8 bvv = *(const s16x8*)&Vt[w*16 + r16][kgrp*8];
        f32x4 o0 = {0,0,0,0}, o1 = {0,0,0,0};
        o0 = MFMA16(ap0, bvv, o0);
        o1 = MFMA16(ap1, bvv, o1);
        #pragma unroll
        for (int mi = 0; mi < 2; ++mi) {
            f32x4 o_ = mi ? o1 : o0;
            #pragma unroll
            for (int r = 0; r < 4; ++r) {
                int i = mi*16 + kgrp*4 + r;
                ctx[(size_t)(b*T_ + i)*D_ + h*HD_ + w*16 + r16] = f2bf(o_[r]);
            }
        }
    }
}

// ---- Wo GEMM + head-part-2: s2p[m][bn] = sum over block's 64 cols of O*Wh2 ----
__global__ __launch_bounds__(256) void gemm_head_kernel(
    const unsigned short* __restrict__ Abf,   // CTXbf [512][768]
    const unsigned short* __restrict__ Wtn,   // Wot [768][768] n-major
    const float* __restrict__ bias,           // bo
    const float* __restrict__ Wh,             // [1536]
    float* __restrict__ s2p)                  // [512][12]
{
    const int bn = blockIdx.x;          // 0..11
    const int n0 = bn * 64;
    const int m0 = blockIdx.y * 64;

    __shared__ unsigned short As[64][40];
    __shared__ unsigned short Bs[64][40];
    __shared__ float s2l[64][2];

    const int tid  = threadIdx.x;
    const int lane = tid & 63;
    const int wave = tid >> 6;
    const int wm   = wave >> 1;
    const int wn   = wave & 1;
    const int kgrp = lane >> 4;
    const int r16  = lane & 15;

    const int srow = tid >> 2;
    const int scol = (tid & 3) * 8;

    f32x4 acc00 = {0,0,0,0}, acc01 = {0,0,0,0}, acc10 = {0,0,0,0}, acc11 = {0,0,0,0};

    for (int k0 = 0; k0 < D_; k0 += 32) {
        s16x8 av = *(const s16x8*)(Abf + (size_t)(m0 + srow)*D_ + k0 + scol);
        s16x8 bv = *(const s16x8*)(Wtn + (size_t)(n0 + srow)*D_ + k0 + scol);
        *(s16x8*)&As[srow][scol] = av;
        *(s16x8*)&Bs[srow][scol] = bv;
        __syncthreads();
        s16x8 a0 = *(const s16x8*)&As[wm*32 +      r16][kgrp*8];
        s16x8 a1 = *(const s16x8*)&As[wm*32 + 16 + r16][kgrp*8];
        s16x8 bb0 = *(const s16x8*)&Bs[wn*32 +      r16][kgrp*8];
        s16x8 bb1 = *(const s16x8*)&Bs[wn*32 + 16 + r16][kgrp*8];
        acc00 = MFMA16(a0, bb0, acc00);
        acc01 = MFMA16(a0, bb1, acc01);
        acc10 = MFMA16(a1, bb0, acc10);
        acc11 = MFMA16(a1, bb1, acc11);
        __syncthreads();
    }

    float rp[2][4] = {};
    #pragma unroll
    for (int ni = 0; ni < 2; ++ni) {
        int col = n0 + wn*32 + ni*16 + r16;
        float w2 = Wh[D_ + col];
        float bv_ = bias[col];
        #pragma unroll
        for (int mi = 0; mi < 2; ++mi) {
            f32x4 c = (mi == 0) ? (ni == 0 ? acc00 : acc01) : (ni == 0 ? acc10 : acc11);
            #pragma unroll
            for (int r = 0; r < 4; ++r) {
                int m = m0 + wm*32 + mi*16 + kgrp*4 + r;
                float v = c[r] + bv_;
                if ((m & (T_ - 1)) == 0) v = 0.f;   // t == 0
                rp[mi][r] = fmaf(v, w2, rp[mi][r]);
            }
        }
    }
    #pragma unroll
    for (int mi = 0; mi < 2; ++mi)
        #pragma unroll
        for (int r = 0; r < 4; ++r) {
            float v = rp[mi][r];
            v += __shfl_xor(v, 1); v += __shfl_xor(v, 2);
            v += __shfl_xor(v, 4); v += __shfl_xor(v, 8);
            rp[mi][r] = v;
        }
    if (r16 == 0) {
        #pragma unroll
        for (int mi = 0; mi < 2; ++mi)
            #pragma unroll
            for (int r = 0; r < 4; ++r)
                s2l[wm*32 + mi*16 + kgrp*4 + r][wn] = rp[mi][r];
    }
    __syncthreads();
    if (tid < 64)
        s2p[(size_t)(m0 + tid)*12 + bn] = s2l[tid][0] + s2l[tid][1];
}

// ---- final: s = s1 + sum(s2p) + bh -> sigmoid*mask -> noisy-or scan ----
__global__ __launch_bounds__(512) void scan_kernel(
    const float* __restrict__ s1, const float* __restrict__ s2p,
    const float* __restrict__ bh, const float* __restrict__ tmask,
    float* __restrict__ qprob, float* __restrict__ p_agg, float* __restrict__ p_dlg)
{
    const int bt = threadIdx.x;        // 0..511, single block
    const int t  = bt & 31, b = bt >> 5;
    float s = s1[bt] + bh[0];
    #pragma unroll
    for (int c = 0; c < 12; ++c) s += s2p[bt*12 + c];
    float q = (1.f / (1.f + __expf(-s))) * tmask[bt];
    qprob[bt] = q;
    float x = 1.f - q;
    #pragma unroll
    for (int off = 1; off < 32; off <<= 1) {
        float y = __shfl_up(x, off, 32);
        if (t >= off) x *= y;
    }
    p_agg[bt] = 1.f - x;
    if (t == 31) p_dlg[b] = 1.f - x;
}

extern "C" void kernel_launch(void* const* d_in, const int* in_sizes, int n_in,
                              void* d_out, int out_size, void* d_ws, size_t ws_size,
                              hipStream_t stream) {
    const int*   ids   = (const int*)  d_in[0];
    const float* amask = (const float*)d_in[1];
    const float* tmask = (const float*)d_in[2];
    const float* embed = (const float*)d_in[3];
    const float* Wq    = (const float*)d_in[4];
    const float* bq    = (const float*)d_in[5];
    const float* Wk    = (const float*)d_in[6];
    const float* bk    = (const float*)d_in[7];
    const float* Wv    = (const float*)d_in[8];
    const float* bv    = (const float*)d_in[9];
    const float* Wo    = (const float*)d_in[10];
    const float* bo    = (const float*)d_in[11];
    const float* Wh    = (const float*)d_in[12];
    const float* bh    = (const float*)d_in[13];
    float* out = (float*)d_out;

    unsigned short* Hbf   = (unsigned short*)d_ws;          // [512][768]
    unsigned short* CTXbf = Hbf + (size_t)M_*D_;            // [512][768]
    unsigned short* Wt    = CTXbf + (size_t)M_*D_;          // [2304][768]
    unsigned short* Wot   = Wt + (size_t)3*D_*D_;           // [768][768]
    float* s1    = (float*)(Wot + (size_t)D_*D_);           // [512]
    float* s2p   = s1 + M_;                                 // [512][12]
    float* PartM = s2p + M_*12;                             // [2048]
    float* Ppart = PartM + M_*4;                            // [2048][768]

    pool_prep_kernel<<<M_*4 + 1536, 384, 0, stream>>>(
        ids, amask, embed, Wq, Wk, Wv, Wo, Wt, Wot, Ppart, PartM);
    combine_kernel<<<M_, 96, 0, stream>>>(Ppart, PartM, Wh, Hbf, s1);
    qkv_attn_kernel<<<B_*NH_, 256, 0, stream>>>(Hbf, Wt, bq, bk, bv, tmask, CTXbf);
    gemm_head_kernel<<<dim3(12, 8), 256, 0, stream>>>(CTXbf, Wot, bo, Wh, s2p);
    scan_kernel<<<1, 512, 0, stream>>>(s1, s2p, bh, tmask, out, out + M_, out + 2*M_);
}